// Round 5
// baseline (325.053 us; speedup 1.0000x reference)
//
#include <hip/hip_runtime.h>
#include <hip/hip_bf16.h>

#define B_ 2
#define N_ 2048
#define E_ 1024
#define H_ 16
#define D_ 64
#define BH_ (B_ * H_)

typedef __attribute__((ext_vector_type(4))) float f32x4;
typedef __attribute__((ext_vector_type(8))) short bf16x8;
typedef __attribute__((ext_vector_type(4))) short s16x4;
typedef __attribute__((ext_vector_type(4))) int i32x4;
typedef __attribute__((ext_vector_type(2))) int i32x2;
typedef __attribute__((ext_vector_type(4))) _Float16 f16x4;

#define MFMA(a, b, c) __builtin_amdgcn_mfma_f32_16x16x32_bf16(a, b, c, 0, 0, 0)
#define MFMA16(a, b, c) __builtin_amdgcn_mfma_f32_16x16x16f16(a, b, c, 0, 0, 0)

#define AS1(p) ((const __attribute__((address_space(1))) unsigned int*)(p))
#define AS3(p) ((__attribute__((address_space(3))) unsigned int*)(p))

static __device__ __forceinline__ int pack2bf(float lo, float hi) {
    __hip_bfloat162 t = __float22bfloat162_rn(float2{lo, hi});
    int r;
    __builtin_memcpy(&r, &t, 4);
    return r;
}
static __device__ __forceinline__ bf16x8 cvt8s(const float* __restrict__ p, float sc) {
    f32x4 a = *(const f32x4*)p;
    f32x4 b = *(const f32x4*)(p + 4);
    i32x4 r = {pack2bf(a.x * sc, a.y * sc), pack2bf(a.z * sc, a.w * sc),
               pack2bf(b.x * sc, b.y * sc), pack2bf(b.z * sc, b.w * sc)};
    return __builtin_bit_cast(bf16x8, r);
}
// 4x f32 -> f16x4 via two v_cvt_pkrtz_f16_f32 (RTZ; P in [0,1], fine)
static __device__ __forceinline__ f16x4 pack4f16(f32x4 p) {
    auto lo = __builtin_amdgcn_cvt_pkrtz(p.x, p.y);   // __fp16 x2
    auto hi = __builtin_amdgcn_cvt_pkrtz(p.z, p.w);
    f16x4 r;
    __builtin_memcpy(&r, &lo, 4);
    __builtin_memcpy(((char*)&r) + 4, &hi, 4);
    return r;
}

// ---------------------------------------------------------------------------
// Fused projections: z=0 -> qh = (q@Wq^T)*log2e/32, masked rows zeroed,
// layout [bh][n][d] bf16; z=1 -> kh [bh][n][d] bf16;
// z=2 -> vt [bh][d][n] in F16 (PV runs f16 16x16x16 MFMA);
// z=3 (when launched with gridDim.z==4) -> Wo fp32 -> bf16 convert.
// grid (N/64, BH, 3|4), block 256.
// ---------------------------------------------------------------------------
__global__ __launch_bounds__(256, 2)
void proj_kernel(const float* __restrict__ q, const float* __restrict__ k,
                 const float* __restrict__ v,
                 const float* __restrict__ Wq, const float* __restrict__ Wk,
                 const float* __restrict__ Wv,
                 const int* __restrict__ mask,
                 const float* __restrict__ Wo,
                 unsigned short* __restrict__ qh, unsigned short* __restrict__ kh,
                 unsigned short* __restrict__ vt, unsigned short* __restrict__ wob) {
    const int z = blockIdx.z;
    if (z == 3) {   // Wo fp32 -> bf16, 1024 blocks x 256 thr x 4 elems
        int idx = (blockIdx.y * 32 + blockIdx.x) * 256 + threadIdx.x;
        f32x4 w = *(const f32x4*)(Wo + (size_t)idx * 4);
        i32x2 r = {pack2bf(w.x, w.y), pack2bf(w.z, w.w)};
        *(i32x2*)(wob + (size_t)idx * 4) = r;
        return;
    }
    const float* X = (z == 0) ? q : (z == 1) ? k : v;
    const float* W = (z == 0) ? Wq : (z == 1) ? Wk : Wv;
    unsigned short* out = (z == 0) ? qh : (z == 1) ? kh : vt;
    const float wscale = (z == 0) ? (1.44269504f * 0.03125f) : 1.0f;

    const int lane = threadIdx.x & 63;
    const int wave = threadIdx.x >> 6;
    const int l16  = lane & 15;
    const int quad = lane >> 4;
    const int bh = blockIdx.y;
    const int b = bh >> 4, h = bh & 15;
    const int n0 = blockIdx.x * 64;
    const int tok = n0 + wave * 16 + l16;

    const float* xrow = X + ((size_t)(b * N_ + tok)) * E_ + h * 64;
    bf16x8 xf[2];
    xf[0] = cvt8s(xrow + quad * 8, 1.0f);
    xf[1] = cvt8s(xrow + 32 + quad * 8, 1.0f);

    const float* Wh = W + (size_t)h * 64 * 64;
    bf16x8 wf[4][2];
#pragma unroll
    for (int t4 = 0; t4 < 4; ++t4) {
        const float* wrow = Wh + (t4 * 16 + l16) * 64;
        wf[t4][0] = cvt8s(wrow + quad * 8, wscale);
        wf[t4][1] = cvt8s(wrow + 32 + quad * 8, wscale);
    }

    const int mk = (z == 0) ? mask[b * N_ + tok] : 1;

#pragma unroll
    for (int mi = 0; mi < 4; ++mi) {
        f32x4 a = {0.f, 0.f, 0.f, 0.f};
        a = MFMA(wf[mi][0], xf[0], a);   // D: row = dout, col = token (l16)
        a = MFMA(wf[mi][1], xf[1], a);
        if (z != 2) {
            i32x2 pk = {pack2bf(a.x, a.y), pack2bf(a.z, a.w)};
            if (!mk) pk = (i32x2){0, 0};
            *(i32x2*)(out + ((size_t)bh * N_ + tok) * 64 + mi * 16 + quad * 4) = pk;
        } else {
#pragma unroll
            for (int r = 0; r < 4; ++r) {
                int dout = mi * 16 + quad * 4 + r;
                _Float16 hv = (_Float16)a[r];
                unsigned short us;
                __builtin_memcpy(&us, &hv, 2);
                out[((size_t)bh * 64 + dout) * N_ + tok] = us;
            }
        }
    }
}

// ---------------------------------------------------------------------------
// Fallback (only if workspace too small for a non-aliased wob).
__global__ __launch_bounds__(256)
void cvt_wo_kernel(const float* __restrict__ wo, unsigned short* __restrict__ wob) {
    int idx = blockIdx.x * 256 + threadIdx.x;
    f32x4 v = *(const f32x4*)(wo + (size_t)idx * 4);
    i32x2 r = {pack2bf(v.x, v.y), pack2bf(v.z, v.w)};
    *(i32x2*)(wob + (size_t)idx * 4) = r;
}

// ---------------------------------------------------------------------------
// Flash attention v4: L2-DIRECT.  r4 post-mortem: the r2 kernel's LDS pipe
// ran ~47% busy (64 b128 + 128 b64 reads + 32 b128 writes per CU-iter) and
// one barrier/iter serialized everything; K/V per XCD (4 heads = 2 MB) is
// L2-resident, per-CU tiles L1-resident -> staging was pure overhead
// (Common-mistake #7).  v4: NO LDS, NO barriers.  Per wave: K frags double-
// buffered in registers (manual 2x unroll, static indexing), V frags loaded
// at iter start and consumed ~500 cyc later by PV (L2 latency hidden by
// QK+softmax), PV delay removed (free-running waves overlap each other).
// Same math, same no-max softmax, same PV-B-layout trick.
// grid (16,32)=512 (4 heads/XCD swizzle), block 256, 2 waves/SIMD.
// ---------------------------------------------------------------------------
__global__ __launch_bounds__(256, 2)
void attn_kernel(const unsigned short* __restrict__ qh,
                 const unsigned short* __restrict__ kh,
                 const unsigned short* __restrict__ vt,
                 unsigned short* __restrict__ attnb) {
    const int tid  = threadIdx.x;
    const int lane = tid & 63;
    const int wave = tid >> 6;
    const int l16  = lane & 15;
    const int quad = lane >> 4;

    const int flat = blockIdx.y * gridDim.x + blockIdx.x;   // 0..511
    const int qblk = flat >> 5;
    const int rem  = flat & 31;
    const int bh   = ((rem & 7) << 2) | (rem >> 3);          // 4 heads per XCD
    const int b = bh >> 4, h = bh & 15;
    const int q0 = qblk * 128 + wave * 32;

    const unsigned short* kbase = kh + (size_t)bh * N_ * 64;
    const unsigned short* vbase = vt + (size_t)bh * 64 * N_;

    // Q frags (regs, whole kernel)
    bf16x8 qf[2][2];
#pragma unroll
    for (int qi = 0; qi < 2; ++qi) {
        const unsigned short* qrow = qh + ((size_t)bh * N_ + q0 + qi * 16 + l16) * 64;
        qf[qi][0] = *(const bf16x8*)(qrow + quad * 8);
        qf[qi][1] = *(const bf16x8*)(qrow + 32 + quad * 8);
    }

    f32x4 psum[2] = {{0.f, 0.f, 0.f, 0.f}, {0.f, 0.f, 0.f, 0.f}};
    f32x4 o[4][2];
#pragma unroll
    for (int mi = 0; mi < 4; ++mi)
#pragma unroll
        for (int qi = 0; qi < 2; ++qi) o[mi][qi] = (f32x4){0.f, 0.f, 0.f, 0.f};

    // K fragment lane offset (elements): row (t4*16+l16), col (half*32+quad*8)
    const int koff = l16 * 64 + quad * 8;
    // V fragment lane base: row d = mi*16+l16, col key = kt*64 + t4*16 + quad*4
    const unsigned short* vrow = vbase + (size_t)l16 * N_ + quad * 4;

    bf16x8 kaA[4][2], kaB[4][2];
    // prologue: K tile 0 -> kaA
    {
        const unsigned short* kp = kbase + koff;
#pragma unroll
        for (int t4 = 0; t4 < 4; ++t4) {
            kaA[t4][0] = *(const bf16x8*)(kp + t4 * 1024);
            kaA[t4][1] = *(const bf16x8*)(kp + t4 * 1024 + 32);
        }
    }

// One k-tile, registers only.  KA_CUR holds K(KT); KA_NXT receives K(KT+1).
#define ATTN_BODY(KT, KA_CUR, KA_NXT)                                            \
    {                                                                            \
        const int ktn = ((KT) + 1 < N_ / 64) ? (KT) + 1 : (N_ / 64 - 1);         \
        const unsigned short* kp = kbase + (size_t)ktn * 4096 + koff;            \
        _Pragma("unroll")                                                        \
        for (int t4 = 0; t4 < 4; ++t4) {                                         \
            KA_NXT[t4][0] = *(const bf16x8*)(kp + t4 * 1024);                    \
            KA_NXT[t4][1] = *(const bf16x8*)(kp + t4 * 1024 + 32);               \
        }                                                                        \
        f16x4 va[4][4];                                                          \
        {                                                                        \
            const unsigned short* vp = vrow + (KT) * 64;                         \
            _Pragma("unroll")                                                    \
            for (int mi = 0; mi < 4; ++mi)                                       \
                _Pragma("unroll")                                                \
                for (int t4 = 0; t4 < 4; ++t4)                                   \
                    va[mi][t4] = *(const f16x4*)(vp + (size_t)mi * 16 * N_ +     \
                                                 t4 * 16);                       \
        }                                                                        \
        __builtin_amdgcn_s_setprio(1);                                           \
        f32x4 s[2][4];                                                           \
        _Pragma("unroll")                                                        \
        for (int qi = 0; qi < 2; ++qi)                                           \
            _Pragma("unroll")                                                    \
            for (int t4 = 0; t4 < 4; ++t4) {                                     \
                f32x4 zz = {0.f, 0.f, 0.f, 0.f};                                 \
                zz = MFMA(KA_CUR[t4][0], qf[qi][0], zz);                         \
                zz = MFMA(KA_CUR[t4][1], qf[qi][1], zz);                         \
                s[qi][t4] = zz;                                                  \
            }                                                                    \
        __builtin_amdgcn_s_setprio(0);                                           \
        f16x4 pf[2][4];                                                          \
        _Pragma("unroll")                                                        \
        for (int qi = 0; qi < 2; ++qi)                                           \
            _Pragma("unroll")                                                    \
            for (int t4 = 0; t4 < 4; ++t4) {                                     \
                f32x4 p;                                                         \
                _Pragma("unroll")                                                \
                for (int r = 0; r < 4; ++r)                                      \
                    p[r] = __builtin_amdgcn_exp2f(s[qi][t4][r]);                 \
                psum[qi] += p;                                                   \
                pf[qi][t4] = pack4f16(p);                                        \
            }                                                                    \
        __builtin_amdgcn_s_setprio(1);                                           \
        _Pragma("unroll")                                                        \
        for (int mi = 0; mi < 4; ++mi)                                           \
            _Pragma("unroll")                                                    \
            for (int t4 = 0; t4 < 4; ++t4)                                       \
                _Pragma("unroll")                                                \
                for (int qi = 0; qi < 2; ++qi)                                   \
                    o[mi][qi] = MFMA16(va[mi][t4], pf[qi][t4], o[mi][qi]);       \
        __builtin_amdgcn_s_setprio(0);                                           \
    }

    for (int kt = 0; kt < N_ / 64; kt += 2) {
        ATTN_BODY(kt, kaA, kaB)
        ATTN_BODY(kt + 1, kaB, kaA)
    }
#undef ATTN_BODY

    // row-sum reduction (once per kernel)
#pragma unroll
    for (int qi = 0; qi < 2; ++qi) {
        float rs = psum[qi].x + psum[qi].y + psum[qi].z + psum[qi].w;
        rs += __shfl_xor(rs, 16);
        rs += __shfl_xor(rs, 32);
        const float inv = 1.0f / rs;
        const int qrow_idx = q0 + qi * 16 + l16;
#pragma unroll
        for (int mi = 0; mi < 4; ++mi) {
            f32x4 ov = o[mi][qi];
            i32x2 pkk = {pack2bf(ov.x * inv, ov.y * inv),
                         pack2bf(ov.z * inv, ov.w * inv)};
            int d0 = mi * 16 + quad * 4;
            *(i32x2*)(attnb + ((size_t)(b * N_ + qrow_idx)) * E_ + h * 64 + d0) = pkk;
        }
    }
}

// ---------------------------------------------------------------------------
// out = attnb(4096x1024 bf16) @ wob^T(1024x1024) -> fp32.  128x128 tile,
// BK=32, global_load_lds w16, dbuf chunk-linear LDS, 512 thr, XCD-chunked
// block mapping (blocks sharing an A row-slab sit on one XCD's L2).
// grid 256 1-D.
// ---------------------------------------------------------------------------
__global__ __launch_bounds__(512, 1)
void out_gemm_kernel(const unsigned short* __restrict__ A,
                     const unsigned short* __restrict__ Bw,
                     float* __restrict__ out) {
    __shared__ short As[2][128 * 32];   // 8 KB each
    __shared__ short Bs[2][128 * 32];

    const int tid  = threadIdx.x;
    const int lane = tid & 63;
    const int l16  = lane & 15;
    const int quad = lane >> 4;
    const int wave = tid >> 6;
    const int wm = wave & 1, wn = wave >> 1;

    const int flat = blockIdx.x;          // 0..255
    const int xcd  = flat & 7;
    const int sub  = flat >> 3;           // 0..31
    const int m0 = (xcd * 4 + (sub >> 3)) * 128;   // 32 m-tiles
    const int n0 = (sub & 7) * 128;                // 8 n-tiles

    const unsigned short* gA = A + (size_t)m0 * E_;
    const unsigned short* gB = Bw + (size_t)n0 * E_;

    f32x4 acc[4][2];
#pragma unroll
    for (int mt = 0; mt < 4; ++mt)
#pragma unroll
        for (int nt = 0; nt < 2; ++nt) acc[mt][nt] = (f32x4){0.f, 0.f, 0.f, 0.f};

    const int cc = tid >> 7, rr = tid & 127;
#define OG_STAGE(buf, k0)                                                        \
    {                                                                            \
        __builtin_amdgcn_global_load_lds(AS1(gA + (size_t)rr * E_ + (k0) + cc * 8), \
                                         AS3(&As[buf][tid * 8]), 16, 0, 0);      \
        __builtin_amdgcn_global_load_lds(AS1(gB + (size_t)rr * E_ + (k0) + cc * 8), \
                                         AS3(&Bs[buf][tid * 8]), 16, 0, 0);      \
    }

    OG_STAGE(0, 0)
    __syncthreads();

    for (int kt = 0; kt < E_ / 32; ++kt) {
        const int cur = kt & 1;
        if (kt + 1 < E_ / 32) OG_STAGE(cur ^ 1, (kt + 1) * 32)

        bf16x8 af[4], bf[2];
#pragma unroll
        for (int mt = 0; mt < 4; ++mt)
            af[mt] = *(const bf16x8*)(&As[cur][(quad * 128 + wm * 64 + mt * 16 + l16) * 8]);
#pragma unroll
        for (int nt = 0; nt < 2; ++nt)
            bf[nt] = *(const bf16x8*)(&Bs[cur][(quad * 128 + wn * 32 + nt * 16 + l16) * 8]);

        __builtin_amdgcn_s_setprio(1);
#pragma unroll
        for (int mt = 0; mt < 4; ++mt)
#pragma unroll
            for (int nt = 0; nt < 2; ++nt)
                acc[mt][nt] = MFMA(af[mt], bf[nt], acc[mt][nt]);
        __builtin_amdgcn_s_setprio(0);

        __syncthreads();
    }

#pragma unroll
    for (int mt = 0; mt < 4; ++mt)
#pragma unroll
        for (int nt = 0; nt < 2; ++nt)
#pragma unroll
            for (int r = 0; r < 4; ++r)
                out[(size_t)(m0 + wm * 64 + mt * 16 + quad * 4 + r) * E_ +
                    n0 + wn * 32 + nt * 16 + l16] = acc[mt][nt][r];
#undef OG_STAGE
}

// ---------------------------------------------------------------------------
extern "C" void kernel_launch(void* const* d_in, const int* in_sizes, int n_in,
                              void* d_out, int out_size, void* d_ws, size_t ws_size,
                              hipStream_t stream) {
    const float* q    = (const float*)d_in[0];
    const float* k    = (const float*)d_in[1];
    const float* v    = (const float*)d_in[2];
    const int*   mask = (const int*)d_in[3];
    const float* Wq   = (const float*)d_in[4];
    const float* Wk   = (const float*)d_in[5];
    const float* Wv   = (const float*)d_in[6];
    const float* Wo   = (const float*)d_in[7];
    float* out = (float*)d_out;

    char* ws = (char*)d_ws;
    unsigned short* qh    = (unsigned short*)(ws);
    unsigned short* kh    = (unsigned short*)(ws + (size_t)8 * 1024 * 1024);
    unsigned short* vt    = (unsigned short*)(ws + (size_t)16 * 1024 * 1024);
    unsigned short* attnb = (unsigned short*)(ws + (size_t)24 * 1024 * 1024);

    const bool fused_wo = ws_size >= (size_t)34 * 1024 * 1024;
    unsigned short* wob = fused_wo ? (unsigned short*)(ws + (size_t)32 * 1024 * 1024)
                                   : (unsigned short*)(ws);

    dim3 blk(256);
    proj_kernel<<<dim3(N_ / 64, BH_, fused_wo ? 4 : 3), blk, 0, stream>>>(
        q, k, v, Wq, Wk, Wv, mask, Wo, qh, kh, vt, wob);
    attn_kernel<<<dim3(16, 32), blk, 0, stream>>>(qh, kh, vt, attnb);
    if (!fused_wo)
        cvt_wo_kernel<<<dim3(E_ * E_ / 1024), blk, 0, stream>>>(Wo, wob);
    out_gemm_kernel<<<dim3(256), dim3(512), 0, stream>>>(attnb, wob, out);
}

// Round 6
// 200.554 us; speedup vs baseline: 1.6208x; 1.6208x over previous
//
#include <hip/hip_runtime.h>
#include <hip/hip_bf16.h>

#define B_ 2
#define N_ 2048
#define E_ 1024
#define H_ 16
#define D_ 64
#define BH_ (B_ * H_)

typedef __attribute__((ext_vector_type(4))) float f32x4;
typedef __attribute__((ext_vector_type(8))) short bf16x8;
typedef __attribute__((ext_vector_type(4))) int i32x4;
typedef __attribute__((ext_vector_type(2))) int i32x2;
typedef __attribute__((ext_vector_type(4))) _Float16 f16x4;

#define MFMA(a, b, c) __builtin_amdgcn_mfma_f32_16x16x32_bf16(a, b, c, 0, 0, 0)
#define MFMA16(a, b, c) __builtin_amdgcn_mfma_f32_16x16x16f16(a, b, c, 0, 0, 0)

#define AS1(p) ((const __attribute__((address_space(1))) unsigned int*)(p))
#define AS3(p) ((__attribute__((address_space(3))) unsigned int*)(p))

static __device__ __forceinline__ int pack2bf(float lo, float hi) {
    __hip_bfloat162 t = __float22bfloat162_rn(float2{lo, hi});
    int r;
    __builtin_memcpy(&r, &t, 4);
    return r;
}
static __device__ __forceinline__ bf16x8 cvt8s(const float* __restrict__ p, float sc) {
    f32x4 a = *(const f32x4*)p;
    f32x4 b = *(const f32x4*)(p + 4);
    i32x4 r = {pack2bf(a.x * sc, a.y * sc), pack2bf(a.z * sc, a.w * sc),
               pack2bf(b.x * sc, b.y * sc), pack2bf(b.z * sc, b.w * sc)};
    return __builtin_bit_cast(bf16x8, r);
}
// 4x f32 -> f16x4 via two v_cvt_pkrtz_f16_f32 (RTZ; P in [0,1], fine)
static __device__ __forceinline__ f16x4 pack4f16(f32x4 p) {
    auto lo = __builtin_amdgcn_cvt_pkrtz(p.x, p.y);   // __fp16 x2
    auto hi = __builtin_amdgcn_cvt_pkrtz(p.z, p.w);
    f16x4 r;
    __builtin_memcpy(&r, &lo, 4);
    __builtin_memcpy(((char*)&r) + 4, &hi, 4);
    return r;
}

// ---------------------------------------------------------------------------
// Fused projections: z=0 -> qh = (q@Wq^T)*log2e/32, masked rows zeroed,
// layout [bh][n][d] bf16; z=1 -> kh [bh][n][d] bf16;
// z=2 -> vt [bh][d][n] in F16 (PV runs f16 16x16x16 MFMA);
// z=3 (when launched with gridDim.z==4) -> Wo fp32 -> bf16 convert.
// grid (N/64, BH, 3|4), block 256.   [r3-proven, untouched]
// ---------------------------------------------------------------------------
__global__ __launch_bounds__(256, 2)
void proj_kernel(const float* __restrict__ q, const float* __restrict__ k,
                 const float* __restrict__ v,
                 const float* __restrict__ Wq, const float* __restrict__ Wk,
                 const float* __restrict__ Wv,
                 const int* __restrict__ mask,
                 const float* __restrict__ Wo,
                 unsigned short* __restrict__ qh, unsigned short* __restrict__ kh,
                 unsigned short* __restrict__ vt, unsigned short* __restrict__ wob) {
    const int z = blockIdx.z;
    if (z == 3) {   // Wo fp32 -> bf16, 1024 blocks x 256 thr x 4 elems
        int idx = (blockIdx.y * 32 + blockIdx.x) * 256 + threadIdx.x;
        f32x4 w = *(const f32x4*)(Wo + (size_t)idx * 4);
        i32x2 r = {pack2bf(w.x, w.y), pack2bf(w.z, w.w)};
        *(i32x2*)(wob + (size_t)idx * 4) = r;
        return;
    }
    const float* X = (z == 0) ? q : (z == 1) ? k : v;
    const float* W = (z == 0) ? Wq : (z == 1) ? Wk : Wv;
    unsigned short* out = (z == 0) ? qh : (z == 1) ? kh : vt;
    const float wscale = (z == 0) ? (1.44269504f * 0.03125f) : 1.0f;

    const int lane = threadIdx.x & 63;
    const int wave = threadIdx.x >> 6;
    const int l16  = lane & 15;
    const int quad = lane >> 4;
    const int bh = blockIdx.y;
    const int b = bh >> 4, h = bh & 15;
    const int n0 = blockIdx.x * 64;
    const int tok = n0 + wave * 16 + l16;

    const float* xrow = X + ((size_t)(b * N_ + tok)) * E_ + h * 64;
    bf16x8 xf[2];
    xf[0] = cvt8s(xrow + quad * 8, 1.0f);
    xf[1] = cvt8s(xrow + 32 + quad * 8, 1.0f);

    const float* Wh = W + (size_t)h * 64 * 64;
    bf16x8 wf[4][2];
#pragma unroll
    for (int t4 = 0; t4 < 4; ++t4) {
        const float* wrow = Wh + (t4 * 16 + l16) * 64;
        wf[t4][0] = cvt8s(wrow + quad * 8, wscale);
        wf[t4][1] = cvt8s(wrow + 32 + quad * 8, wscale);
    }

    const int mk = (z == 0) ? mask[b * N_ + tok] : 1;

#pragma unroll
    for (int mi = 0; mi < 4; ++mi) {
        f32x4 a = {0.f, 0.f, 0.f, 0.f};
        a = MFMA(wf[mi][0], xf[0], a);   // D: row = dout, col = token (l16)
        a = MFMA(wf[mi][1], xf[1], a);
        if (z != 2) {
            i32x2 pk = {pack2bf(a.x, a.y), pack2bf(a.z, a.w)};
            if (!mk) pk = (i32x2){0, 0};
            *(i32x2*)(out + ((size_t)bh * N_ + tok) * 64 + mi * 16 + quad * 4) = pk;
        } else {
#pragma unroll
            for (int r = 0; r < 4; ++r) {
                int dout = mi * 16 + quad * 4 + r;
                _Float16 hv = (_Float16)a[r];
                unsigned short us;
                __builtin_memcpy(&us, &hv, 2);
                out[((size_t)bh * 64 + dout) * N_ + tok] = us;
            }
        }
    }
}

// ---------------------------------------------------------------------------
// Fallback (only if workspace too small for a non-aliased wob).
__global__ __launch_bounds__(256)
void cvt_wo_kernel(const float* __restrict__ wo, unsigned short* __restrict__ wob) {
    int idx = blockIdx.x * 256 + threadIdx.x;
    f32x4 v = *(const f32x4*)(wo + (size_t)idx * 4);
    i32x2 r = {pack2bf(v.x, v.y), pack2bf(v.z, v.w)};
    *(i32x2*)(wob + (size_t)idx * 4) = r;
}

// ---------------------------------------------------------------------------
// Flash attention v5: r2-proven access patterns + KVBLK=128 (barriers 32->16).
// r5 post-mortem: LDS staging is the coalescing gather engine (L2-direct
// frag loads = 8B/lane scattered -> 180us); keep it.  r2's ~30% stall is the
// per-iter barrier drain -> amortize over 2x keys per iter (m93 direction).
// K dbuf [128][72] (36KB); V dbuf [64][140] x2 (35KB) -> 71KB, 2 blocks/CU.
// V-triple -> dbuf is safe because PV(t) now runs in-iter (after softmax),
// so V(t+1) overwrites V(t-1)'s buffer (consumed last iter); one barrier.
// Two 64-key halves per iter, each = the r2 inner body verbatim (identical
// per-instruction LDS bank behavior).  setprio around MFMA clusters.
// grid (16,32)=512 (4 heads/XCD swizzle), block 256.
// ---------------------------------------------------------------------------
__global__ __launch_bounds__(256, 2)
void attn_kernel(const unsigned short* __restrict__ qh,
                 const unsigned short* __restrict__ kh,
                 const unsigned short* __restrict__ vt,
                 unsigned short* __restrict__ attnb) {
    __shared__ short Kb[2][128 * 72];   // 36 KB
    __shared__ short Vb[2][64 * 140];   // 35 KB

    const int tid  = threadIdx.x;
    const int lane = tid & 63;
    const int l16  = lane & 15;
    const int quad = lane >> 4;
    const int wave = tid >> 6;

    const int flat = blockIdx.y * gridDim.x + blockIdx.x;   // 0..511
    const int qblk = flat >> 5;
    const int rem  = flat & 31;
    const int bh   = ((rem & 7) << 2) | (rem >> 3);          // 4 heads per XCD
    const int b = bh >> 4, h = bh & 15;
    const int q0 = qblk * 128 + wave * 32;

    const unsigned short* kbase = kh + (size_t)bh * N_ * 64;
    const unsigned short* vbase = vt + (size_t)bh * 64 * N_;

    // staging offsets: thread handles chunks tid + j*256 (j=0..3)
    const int ko = (tid >> 3) * 72 + (tid & 7) * 8;     // + j*2304
    const int vo = (tid >> 4) * 140 + (tid & 15) * 8;   // + j*2240
    const int vd = tid >> 4;                            // V source row (d), + j*16
    const int vc = (tid & 15) * 8;                      // V source col8

    short* kcur  = &Kb[0][0];
    short* knext = &Kb[1][0];
    short* vcur  = &Vb[0][0];
    short* vnext = &Vb[1][0];

    bf16x8 qf[2][2];
#pragma unroll
    for (int qi = 0; qi < 2; ++qi) {
        const unsigned short* qrow = qh + ((size_t)bh * N_ + q0 + qi * 16 + l16) * 64;
        qf[qi][0] = *(const bf16x8*)(qrow + quad * 8);
        qf[qi][1] = *(const bf16x8*)(qrow + 32 + quad * 8);
    }

    f32x4 psum[2] = {{0.f, 0.f, 0.f, 0.f}, {0.f, 0.f, 0.f, 0.f}};
    f32x4 o[4][2];
#pragma unroll
    for (int mi = 0; mi < 4; ++mi)
#pragma unroll
        for (int qi = 0; qi < 2; ++qi) o[mi][qi] = (f32x4){0.f, 0.f, 0.f, 0.f};

    bf16x8 gK[4], gV[4];
    // stage tile 0 (K: 128x64 row-contiguous; V: [d=64][key=128])
#pragma unroll
    for (int j = 0; j < 4; ++j) {
        gK[j] = *(const bf16x8*)(kbase + (size_t)(tid + j * 256) * 8);
        gV[j] = *(const bf16x8*)(vbase + (size_t)(vd + j * 16) * N_ + vc);
    }
#pragma unroll
    for (int j = 0; j < 4; ++j) {
        *(bf16x8*)(kcur + ko + j * 2304) = gK[j];
        *(bf16x8*)(vcur + vo + j * 2240) = gV[j];
    }
    __syncthreads();

    const int NT2 = N_ / 128;   // 16 outer iterations
    for (int T = 0; T < NT2; ++T) {
        // global prefetch of tile T+1
        if (T + 1 < NT2) {
#pragma unroll
            for (int j = 0; j < 4; ++j) {
                gK[j] = *(const bf16x8*)(kbase + (size_t)(T + 1) * 8192 +
                                         (size_t)(tid + j * 256) * 8);
                gV[j] = *(const bf16x8*)(vbase + (size_t)(vd + j * 16) * N_ +
                                         (T + 1) * 128 + vc);
            }
        }

        // two 64-key halves; each half = r2 inner body
#pragma unroll
        for (int hh = 0; hh < 2; ++hh) {
            // K frags + QK^T
            __builtin_amdgcn_s_setprio(1);
            bf16x8 ka[4][2];
#pragma unroll
            for (int t4 = 0; t4 < 4; ++t4) {
                const int row = hh * 64 + t4 * 16 + l16;
                ka[t4][0] = *(const bf16x8*)(kcur + row * 72 + quad * 8);
                ka[t4][1] = *(const bf16x8*)(kcur + row * 72 + 32 + quad * 8);
            }
            f32x4 s[2][4];
#pragma unroll
            for (int qi = 0; qi < 2; ++qi)
#pragma unroll
                for (int t4 = 0; t4 < 4; ++t4) {
                    f32x4 z = {0.f, 0.f, 0.f, 0.f};
                    z = MFMA(ka[t4][0], qf[qi][0], z);
                    z = MFMA(ka[t4][1], qf[qi][1], z);
                    s[qi][t4] = z;
                }
            __builtin_amdgcn_s_setprio(0);

            // softmax -> pf (NO transform: C-layout == 16x16x16 B-layout)
            f16x4 pf[2][4];
#pragma unroll
            for (int qi = 0; qi < 2; ++qi)
#pragma unroll
                for (int t4 = 0; t4 < 4; ++t4) {
                    f32x4 p;
#pragma unroll
                    for (int r = 0; r < 4; ++r)
                        p[r] = __builtin_amdgcn_exp2f(s[qi][t4][r]);
                    psum[qi] += p;
                    pf[qi][t4] = pack4f16(p);
                }

            // PV for this half (V(T) staged last iter)
            __builtin_amdgcn_s_setprio(1);
#pragma unroll
            for (int mi = 0; mi < 4; ++mi) {
#pragma unroll
                for (int t4 = 0; t4 < 4; ++t4) {
                    f16x4 va = *(const f16x4*)(vcur + (mi * 16 + l16) * 140 +
                                               hh * 64 + t4 * 16 + quad * 4);
#pragma unroll
                    for (int qi = 0; qi < 2; ++qi)
                        o[mi][qi] = MFMA16(va, pf[qi][t4], o[mi][qi]);
                }
            }
            __builtin_amdgcn_s_setprio(0);
        }

        // stage tile T+1, one barrier
        if (T + 1 < NT2) {
#pragma unroll
            for (int j = 0; j < 4; ++j) {
                *(bf16x8*)(knext + ko + j * 2304) = gK[j];
                *(bf16x8*)(vnext + vo + j * 2240) = gV[j];
            }
            __syncthreads();
        }

        short* t = kcur; kcur = knext; knext = t;
        short* tv = vcur; vcur = vnext; vnext = tv;
    }

    // row-sum reduction (once per kernel)
#pragma unroll
    for (int qi = 0; qi < 2; ++qi) {
        float rs = psum[qi].x + psum[qi].y + psum[qi].z + psum[qi].w;
        rs += __shfl_xor(rs, 16);
        rs += __shfl_xor(rs, 32);
        const float inv = 1.0f / rs;
        const int qrow_idx = q0 + qi * 16 + l16;
#pragma unroll
        for (int mi = 0; mi < 4; ++mi) {
            f32x4 ov = o[mi][qi];
            i32x2 pkk = {pack2bf(ov.x * inv, ov.y * inv),
                         pack2bf(ov.z * inv, ov.w * inv)};
            int d0 = mi * 16 + quad * 4;
            *(i32x2*)(attnb + ((size_t)(b * N_ + qrow_idx)) * E_ + h * 64 + d0) = pkk;
        }
    }
}

// ---------------------------------------------------------------------------
// out = attnb(4096x1024 bf16) @ wob^T(1024x1024) -> fp32.  128x128 tile,
// BK=32, global_load_lds w16, dbuf chunk-linear LDS, 512 thr, XCD-chunked
// block mapping (blocks sharing an A row-slab sit on one XCD's L2).
// grid 256 1-D.   [r3-proven, untouched]
// ---------------------------------------------------------------------------
__global__ __launch_bounds__(512, 1)
void out_gemm_kernel(const unsigned short* __restrict__ A,
                     const unsigned short* __restrict__ Bw,
                     float* __restrict__ out) {
    __shared__ short As[2][128 * 32];   // 8 KB each
    __shared__ short Bs[2][128 * 32];

    const int tid  = threadIdx.x;
    const int lane = tid & 63;
    const int l16  = lane & 15;
    const int quad = lane >> 4;
    const int wave = tid >> 6;
    const int wm = wave & 1, wn = wave >> 1;

    const int flat = blockIdx.x;          // 0..255
    const int xcd  = flat & 7;
    const int sub  = flat >> 3;           // 0..31
    const int m0 = (xcd * 4 + (sub >> 3)) * 128;   // 32 m-tiles
    const int n0 = (sub & 7) * 128;                // 8 n-tiles

    const unsigned short* gA = A + (size_t)m0 * E_;
    const unsigned short* gB = Bw + (size_t)n0 * E_;

    f32x4 acc[4][2];
#pragma unroll
    for (int mt = 0; mt < 4; ++mt)
#pragma unroll
        for (int nt = 0; nt < 2; ++nt) acc[mt][nt] = (f32x4){0.f, 0.f, 0.f, 0.f};

    const int cc = tid >> 7, rr = tid & 127;
#define OG_STAGE(buf, k0)                                                        \
    {                                                                            \
        __builtin_amdgcn_global_load_lds(AS1(gA + (size_t)rr * E_ + (k0) + cc * 8), \
                                         AS3(&As[buf][tid * 8]), 16, 0, 0);      \
        __builtin_amdgcn_global_load_lds(AS1(gB + (size_t)rr * E_ + (k0) + cc * 8), \
                                         AS3(&Bs[buf][tid * 8]), 16, 0, 0);      \
    }

    OG_STAGE(0, 0)
    __syncthreads();

    for (int kt = 0; kt < E_ / 32; ++kt) {
        const int cur = kt & 1;
        if (kt + 1 < E_ / 32) OG_STAGE(cur ^ 1, (kt + 1) * 32)

        bf16x8 af[4], bf[2];
#pragma unroll
        for (int mt = 0; mt < 4; ++mt)
            af[mt] = *(const bf16x8*)(&As[cur][(quad * 128 + wm * 64 + mt * 16 + l16) * 8]);
#pragma unroll
        for (int nt = 0; nt < 2; ++nt)
            bf[nt] = *(const bf16x8*)(&Bs[cur][(quad * 128 + wn * 32 + nt * 16 + l16) * 8]);

        __builtin_amdgcn_s_setprio(1);
#pragma unroll
        for (int mt = 0; mt < 4; ++mt)
#pragma unroll
            for (int nt = 0; nt < 2; ++nt)
                acc[mt][nt] = MFMA(af[mt], bf[nt], acc[mt][nt]);
        __builtin_amdgcn_s_setprio(0);

        __syncthreads();
    }

#pragma unroll
    for (int mt = 0; mt < 4; ++mt)
#pragma unroll
        for (int nt = 0; nt < 2; ++nt)
#pragma unroll
            for (int r = 0; r < 4; ++r)
                out[(size_t)(m0 + wm * 64 + mt * 16 + quad * 4 + r) * E_ +
                    n0 + wn * 32 + nt * 16 + l16] = acc[mt][nt][r];
#undef OG_STAGE
}

// ---------------------------------------------------------------------------
extern "C" void kernel_launch(void* const* d_in, const int* in_sizes, int n_in,
                              void* d_out, int out_size, void* d_ws, size_t ws_size,
                              hipStream_t stream) {
    const float* q    = (const float*)d_in[0];
    const float* k    = (const float*)d_in[1];
    const float* v    = (const float*)d_in[2];
    const int*   mask = (const int*)d_in[3];
    const float* Wq   = (const float*)d_in[4];
    const float* Wk   = (const float*)d_in[5];
    const float* Wv   = (const float*)d_in[6];
    const float* Wo   = (const float*)d_in[7];
    float* out = (float*)d_out;

    char* ws = (char*)d_ws;
    unsigned short* qh    = (unsigned short*)(ws);
    unsigned short* kh    = (unsigned short*)(ws + (size_t)8 * 1024 * 1024);
    unsigned short* vt    = (unsigned short*)(ws + (size_t)16 * 1024 * 1024);
    unsigned short* attnb = (unsigned short*)(ws + (size_t)24 * 1024 * 1024);

    const bool fused_wo = ws_size >= (size_t)34 * 1024 * 1024;
    unsigned short* wob = fused_wo ? (unsigned short*)(ws + (size_t)32 * 1024 * 1024)
                                   : (unsigned short*)(ws);

    dim3 blk(256);
    proj_kernel<<<dim3(N_ / 64, BH_, fused_wo ? 4 : 3), blk, 0, stream>>>(
        q, k, v, Wq, Wk, Wv, mask, Wo, qh, kh, vt, wob);
    attn_kernel<<<dim3(16, 32), blk, 0, stream>>>(qh, kh, vt, attnb);
    if (!fused_wo)
        cvt_wo_kernel<<<dim3(E_ * E_ / 1024), blk, 0, stream>>>(Wo, wob);
    out_gemm_kernel<<<dim3(256), dim3(512), 0, stream>>>(attnb, wob, out);
}

// Round 7
// 196.224 us; speedup vs baseline: 1.6565x; 1.0221x over previous
//
#include <hip/hip_runtime.h>
#include <hip/hip_bf16.h>

#define B_ 2
#define N_ 2048
#define E_ 1024
#define H_ 16
#define D_ 64
#define BH_ (B_ * H_)

typedef __attribute__((ext_vector_type(4))) float f32x4;
typedef __attribute__((ext_vector_type(8))) short bf16x8;
typedef __attribute__((ext_vector_type(4))) short s16x4;
typedef __attribute__((ext_vector_type(4))) int i32x4;
typedef __attribute__((ext_vector_type(2))) int i32x2;
typedef __attribute__((ext_vector_type(4))) _Float16 f16x4;

#define MFMA(a, b, c) __builtin_amdgcn_mfma_f32_16x16x32_bf16(a, b, c, 0, 0, 0)
#define MFMA16(a, b, c) __builtin_amdgcn_mfma_f32_16x16x16f16(a, b, c, 0, 0, 0)

#define AS1(p) ((const __attribute__((address_space(1))) unsigned int*)(p))
#define AS3(p) ((__attribute__((address_space(3))) unsigned int*)(p))

static __device__ __forceinline__ int pack2bf(float lo, float hi) {
    __hip_bfloat162 t = __float22bfloat162_rn(float2{lo, hi});
    int r;
    __builtin_memcpy(&r, &t, 4);
    return r;
}
static __device__ __forceinline__ bf16x8 cvt8s(const float* __restrict__ p, float sc) {
    f32x4 a = *(const f32x4*)p;
    f32x4 b = *(const f32x4*)(p + 4);
    i32x4 r = {pack2bf(a.x * sc, a.y * sc), pack2bf(a.z * sc, a.w * sc),
               pack2bf(b.x * sc, b.y * sc), pack2bf(b.z * sc, b.w * sc)};
    return __builtin_bit_cast(bf16x8, r);
}
// 4x f32 -> f16x4 via two v_cvt_pkrtz_f16_f32 (RTZ; P in [0,1], fine)
static __device__ __forceinline__ f16x4 pack4f16(f32x4 p) {
    auto lo = __builtin_amdgcn_cvt_pkrtz(p.x, p.y);   // __fp16 x2
    auto hi = __builtin_amdgcn_cvt_pkrtz(p.z, p.w);
    f16x4 r;
    __builtin_memcpy(&r, &lo, 4);
    __builtin_memcpy(((char*)&r) + 4, &hi, 4);
    return r;
}

// ---------------------------------------------------------------------------
// Fused projections: z=0 -> qh = (q@Wq^T)*log2e/32, masked rows zeroed,
// layout [bh][n][d] bf16; z=1 -> kh [bh][n][d] bf16;
// z=2 -> vt [bh][d][n] in F16 (PV runs f16 16x16x16 MFMA);
// z=3 (when launched with gridDim.z==4) -> Wo fp32 -> bf16 convert.
// grid (N/64, BH, 3|4), block 256.   [r3-proven]
// ---------------------------------------------------------------------------
__global__ __launch_bounds__(256, 2)
void proj_kernel(const float* __restrict__ q, const float* __restrict__ k,
                 const float* __restrict__ v,
                 const float* __restrict__ Wq, const float* __restrict__ Wk,
                 const float* __restrict__ Wv,
                 const int* __restrict__ mask,
                 const float* __restrict__ Wo,
                 unsigned short* __restrict__ qh, unsigned short* __restrict__ kh,
                 unsigned short* __restrict__ vt, unsigned short* __restrict__ wob) {
    const int z = blockIdx.z;
    if (z == 3) {   // Wo fp32 -> bf16, 1024 blocks x 256 thr x 4 elems
        int idx = (blockIdx.y * 32 + blockIdx.x) * 256 + threadIdx.x;
        f32x4 w = *(const f32x4*)(Wo + (size_t)idx * 4);
        i32x2 r = {pack2bf(w.x, w.y), pack2bf(w.z, w.w)};
        *(i32x2*)(wob + (size_t)idx * 4) = r;
        return;
    }
    const float* X = (z == 0) ? q : (z == 1) ? k : v;
    const float* W = (z == 0) ? Wq : (z == 1) ? Wk : Wv;
    unsigned short* out = (z == 0) ? qh : (z == 1) ? kh : vt;
    const float wscale = (z == 0) ? (1.44269504f * 0.03125f) : 1.0f;

    const int lane = threadIdx.x & 63;
    const int wave = threadIdx.x >> 6;
    const int l16  = lane & 15;
    const int quad = lane >> 4;
    const int bh = blockIdx.y;
    const int b = bh >> 4, h = bh & 15;
    const int n0 = blockIdx.x * 64;
    const int tok = n0 + wave * 16 + l16;

    const float* xrow = X + ((size_t)(b * N_ + tok)) * E_ + h * 64;
    bf16x8 xf[2];
    xf[0] = cvt8s(xrow + quad * 8, 1.0f);
    xf[1] = cvt8s(xrow + 32 + quad * 8, 1.0f);

    const float* Wh = W + (size_t)h * 64 * 64;
    bf16x8 wf[4][2];
#pragma unroll
    for (int t4 = 0; t4 < 4; ++t4) {
        const float* wrow = Wh + (t4 * 16 + l16) * 64;
        wf[t4][0] = cvt8s(wrow + quad * 8, wscale);
        wf[t4][1] = cvt8s(wrow + 32 + quad * 8, wscale);
    }

    const int mk = (z == 0) ? mask[b * N_ + tok] : 1;

#pragma unroll
    for (int mi = 0; mi < 4; ++mi) {
        f32x4 a = {0.f, 0.f, 0.f, 0.f};
        a = MFMA(wf[mi][0], xf[0], a);   // D: row = dout, col = token (l16)
        a = MFMA(wf[mi][1], xf[1], a);
        if (z != 2) {
            i32x2 pk = {pack2bf(a.x, a.y), pack2bf(a.z, a.w)};
            if (!mk) pk = (i32x2){0, 0};
            *(i32x2*)(out + ((size_t)bh * N_ + tok) * 64 + mi * 16 + quad * 4) = pk;
        } else {
#pragma unroll
            for (int r = 0; r < 4; ++r) {
                int dout = mi * 16 + quad * 4 + r;
                _Float16 hv = (_Float16)a[r];
                unsigned short us;
                __builtin_memcpy(&us, &hv, 2);
                out[((size_t)bh * 64 + dout) * N_ + tok] = us;
            }
        }
    }
}

// ---------------------------------------------------------------------------
// Fallback (only if workspace too small for a non-aliased wob).
__global__ __launch_bounds__(256)
void cvt_wo_kernel(const float* __restrict__ wo, unsigned short* __restrict__ wob) {
    int idx = blockIdx.x * 256 + threadIdx.x;
    f32x4 v = *(const f32x4*)(wo + (size_t)idx * 4);
    i32x2 r = {pack2bf(v.x, v.y), pack2bf(v.z, v.w)};
    *(i32x2*)(wob + (size_t)idx * 4) = r;
}

// ---------------------------------------------------------------------------
// Flash attention (r2-proven structure, measured 54.6 us; FROZEN).
// PV uses v_mfma_f32_16x16x16_f16 whose B-operand layout EQUALS the QK C/D
// layout -> P needs NO cross-lane transform.  V stored/staged as f16.
// K dbuf [64][72]; V triple-buffer [64][76] (2-way residue conflicts only).
// PV(t-1) pipelined behind QK(t) as an independent dependency chain.
// No-max softmax; qh pre-scaled+masked at proj.  One barrier/iter.
// grid (16,32)=512 (XCD swizzle: 4 heads/XCD).  setprio around MFMA.
// Falsified alternatives: DMA staging+128-thr blocks (67.5), 64q/3blk
// (73.2), L2-direct no-LDS (180.7), KVBLK=128 (57.4).
// ---------------------------------------------------------------------------
__global__ __launch_bounds__(256, 2)
void attn_kernel(const unsigned short* __restrict__ qh,
                 const unsigned short* __restrict__ kh,
                 const unsigned short* __restrict__ vt,
                 unsigned short* __restrict__ attnb) {
    __shared__ short Kb[2][64 * 72];   // 18 KB
    __shared__ short Vb[3][64 * 76];   // 28.5 KB

    const int tid  = threadIdx.x;
    const int lane = tid & 63;
    const int wave = tid >> 6;
    const int l16  = lane & 15;
    const int quad = lane >> 4;

    const int flat = blockIdx.y * gridDim.x + blockIdx.x;   // 0..511
    const int qblk = flat >> 5;
    const int rem  = flat & 31;
    const int bh   = ((rem & 7) << 2) | (rem >> 3);          // 4 heads per XCD
    const int b = bh >> 4, h = bh & 15;
    const int q0 = qblk * 128 + wave * 32;

    const unsigned short* kbase = kh + (size_t)bh * N_ * 64;
    const unsigned short* vbase = vt + (size_t)bh * 64 * N_;

    const int c0i = tid;
    const int c1i = tid + 256;
    const int k0o = (c0i >> 3) * 72 + (c0i & 7) * 8;
    const int k1o = (c1i >> 3) * 72 + (c1i & 7) * 8;
    const int v0o = (c0i >> 3) * 76 + (c0i & 7) * 8;
    const int v1o = (c1i >> 3) * 76 + (c1i & 7) * 8;

    short* kcur  = &Kb[0][0];
    short* knext = &Kb[1][0];
    short* vprev = &Vb[2][0];
    short* vcur  = &Vb[0][0];
    short* vnext = &Vb[1][0];

    bf16x8 qf[2][2];
#pragma unroll
    for (int qi = 0; qi < 2; ++qi) {
        const unsigned short* qrow = qh + ((size_t)bh * N_ + q0 + qi * 16 + l16) * 64;
        qf[qi][0] = *(const bf16x8*)(qrow + quad * 8);
        qf[qi][1] = *(const bf16x8*)(qrow + 32 + quad * 8);
    }

    f32x4 psum[2] = {{0.f, 0.f, 0.f, 0.f}, {0.f, 0.f, 0.f, 0.f}};
    f32x4 o[4][2];
#pragma unroll
    for (int mi = 0; mi < 4; ++mi)
#pragma unroll
        for (int qi = 0; qi < 2; ++qi) o[mi][qi] = (f32x4){0.f, 0.f, 0.f, 0.f};

    f16x4 pf[2][4];   // saved P frags (16x16x16 B-operand) from previous tile

    // stage tile 0
    bf16x8 gK0, gK1, gV0, gV1;
    gK0 = *(const bf16x8*)(kbase + c0i * 8);
    gK1 = *(const bf16x8*)(kbase + c1i * 8);
    gV0 = *(const bf16x8*)(vbase + (size_t)(c0i >> 3) * N_ + (c0i & 7) * 8);
    gV1 = *(const bf16x8*)(vbase + (size_t)(c1i >> 3) * N_ + (c1i & 7) * 8);
    *(bf16x8*)(kcur + k0o) = gK0;
    *(bf16x8*)(kcur + k1o) = gK1;
    *(bf16x8*)(vcur + v0o) = gV0;
    *(bf16x8*)(vcur + v1o) = gV1;
    __syncthreads();

    for (int kt = 0; kt < N_ / 64; ++kt) {
        // global prefetch of tile kt+1
        if (kt + 1 < N_ / 64) {
            const int k0n = (kt + 1) * 64;
            gK0 = *(const bf16x8*)(kbase + (size_t)k0n * 64 + c0i * 8);
            gK1 = *(const bf16x8*)(kbase + (size_t)k0n * 64 + c1i * 8);
            gV0 = *(const bf16x8*)(vbase + (size_t)(c0i >> 3) * N_ + k0n + (c0i & 7) * 8);
            gV1 = *(const bf16x8*)(vbase + (size_t)(c1i >> 3) * N_ + k0n + (c1i & 7) * 8);
        }

        // K frags + QK^T for tile kt  (high prio: MFMA cluster)
        __builtin_amdgcn_s_setprio(1);
        bf16x8 ka[4][2];
#pragma unroll
        for (int t4 = 0; t4 < 4; ++t4) {
            ka[t4][0] = *(const bf16x8*)(kcur + (t4 * 16 + l16) * 72 + quad * 8);
            ka[t4][1] = *(const bf16x8*)(kcur + (t4 * 16 + l16) * 72 + 32 + quad * 8);
        }
        f32x4 s[2][4];
#pragma unroll
        for (int qi = 0; qi < 2; ++qi)
#pragma unroll
            for (int t4 = 0; t4 < 4; ++t4) {
                f32x4 z = {0.f, 0.f, 0.f, 0.f};
                z = MFMA(ka[t4][0], qf[qi][0], z);
                z = MFMA(ka[t4][1], qf[qi][1], z);
                s[qi][t4] = z;
            }

        // PV for tile kt-1 (independent of this iter's chain)
        if (kt > 0) {
#pragma unroll
            for (int mi = 0; mi < 4; ++mi) {
#pragma unroll
                for (int t4 = 0; t4 < 4; ++t4) {
                    f16x4 va = *(const f16x4*)(vprev + (mi * 16 + l16) * 76 +
                                               t4 * 16 + quad * 4);
#pragma unroll
                    for (int qi = 0; qi < 2; ++qi)
                        o[mi][qi] = MFMA16(va, pf[qi][t4], o[mi][qi]);
                }
            }
        }
        __builtin_amdgcn_s_setprio(0);

        // softmax tile kt -> pf (NO transform: C-layout == 16x16x16 B-layout)
#pragma unroll
        for (int qi = 0; qi < 2; ++qi) {
#pragma unroll
            for (int t4 = 0; t4 < 4; ++t4) {
                f32x4 p;
#pragma unroll
                for (int r = 0; r < 4; ++r) p[r] = __builtin_amdgcn_exp2f(s[qi][t4][r]);
                psum[qi] += p;
                pf[qi][t4] = pack4f16(p);
            }
        }

        // stage tile kt+1, one barrier
        if (kt + 1 < N_ / 64) {
            *(bf16x8*)(knext + k0o) = gK0;
            *(bf16x8*)(knext + k1o) = gK1;
            *(bf16x8*)(vnext + v0o) = gV0;
            *(bf16x8*)(vnext + v1o) = gV1;
            __syncthreads();
        }

        // rotate buffers
        short* t = kcur; kcur = knext; knext = t;
        short* tv = vprev; vprev = vcur; vcur = vnext; vnext = tv;
    }

    // drain: PV for the last tile
    __builtin_amdgcn_s_setprio(1);
#pragma unroll
    for (int mi = 0; mi < 4; ++mi) {
#pragma unroll
        for (int t4 = 0; t4 < 4; ++t4) {
            f16x4 va = *(const f16x4*)(vprev + (mi * 16 + l16) * 76 +
                                       t4 * 16 + quad * 4);
#pragma unroll
            for (int qi = 0; qi < 2; ++qi)
                o[mi][qi] = MFMA16(va, pf[qi][t4], o[mi][qi]);
        }
    }
    __builtin_amdgcn_s_setprio(0);

    // row-sum reduction (once per kernel, not per iter)
#pragma unroll
    for (int qi = 0; qi < 2; ++qi) {
        float rs = psum[qi].x + psum[qi].y + psum[qi].z + psum[qi].w;
        rs += __shfl_xor(rs, 16);
        rs += __shfl_xor(rs, 32);
        const float inv = 1.0f / rs;
        const int qrow_idx = q0 + qi * 16 + l16;
#pragma unroll
        for (int mi = 0; mi < 4; ++mi) {
            f32x4 ov = o[mi][qi];
            i32x2 pkk = {pack2bf(ov.x * inv, ov.y * inv),
                         pack2bf(ov.z * inv, ov.w * inv)};
            int d0 = mi * 16 + quad * 4;
            *(i32x2*)(attnb + ((size_t)(b * N_ + qrow_idx)) * E_ + h * 64 + d0) = pkk;
        }
    }
}

// ---------------------------------------------------------------------------
// out = attnb(4096x1024 bf16) @ wob^T(1024x1024) -> fp32.  128x128 tile,
// BK=32, global_load_lds w16, dbuf chunk-linear LDS, 512 thr, XCD-chunked
// block mapping (blocks sharing an A row-slab sit on one XCD's L2).
// grid 256 1-D.   [r3-proven]
// ---------------------------------------------------------------------------
__global__ __launch_bounds__(512, 1)
void out_gemm_kernel(const unsigned short* __restrict__ A,
                     const unsigned short* __restrict__ Bw,
                     float* __restrict__ out) {
    __shared__ short As[2][128 * 32];   // 8 KB each
    __shared__ short Bs[2][128 * 32];

    const int tid  = threadIdx.x;
    const int lane = tid & 63;
    const int l16  = lane & 15;
    const int quad = lane >> 4;
    const int wave = tid >> 6;
    const int wm = wave & 1, wn = wave >> 1;

    const int flat = blockIdx.x;          // 0..255
    const int xcd  = flat & 7;
    const int sub  = flat >> 3;           // 0..31
    const int m0 = (xcd * 4 + (sub >> 3)) * 128;   // 32 m-tiles
    const int n0 = (sub & 7) * 128;                // 8 n-tiles

    const unsigned short* gA = A + (size_t)m0 * E_;
    const unsigned short* gB = Bw + (size_t)n0 * E_;

    f32x4 acc[4][2];
#pragma unroll
    for (int mt = 0; mt < 4; ++mt)
#pragma unroll
        for (int nt = 0; nt < 2; ++nt) acc[mt][nt] = (f32x4){0.f, 0.f, 0.f, 0.f};

    const int cc = tid >> 7, rr = tid & 127;
#define OG_STAGE(buf, k0)                                                        \
    {                                                                            \
        __builtin_amdgcn_global_load_lds(AS1(gA + (size_t)rr * E_ + (k0) + cc * 8), \
                                         AS3(&As[buf][tid * 8]), 16, 0, 0);      \
        __builtin_amdgcn_global_load_lds(AS1(gB + (size_t)rr * E_ + (k0) + cc * 8), \
                                         AS3(&Bs[buf][tid * 8]), 16, 0, 0);      \
    }

    OG_STAGE(0, 0)
    __syncthreads();

    for (int kt = 0; kt < E_ / 32; ++kt) {
        const int cur = kt & 1;
        if (kt + 1 < E_ / 32) OG_STAGE(cur ^ 1, (kt + 1) * 32)

        bf16x8 af[4], bf[2];
#pragma unroll
        for (int mt = 0; mt < 4; ++mt)
            af[mt] = *(const bf16x8*)(&As[cur][(quad * 128 + wm * 64 + mt * 16 + l16) * 8]);
#pragma unroll
        for (int nt = 0; nt < 2; ++nt)
            bf[nt] = *(const bf16x8*)(&Bs[cur][(quad * 128 + wn * 32 + nt * 16 + l16) * 8]);

        __builtin_amdgcn_s_setprio(1);
#pragma unroll
        for (int mt = 0; mt < 4; ++mt)
#pragma unroll
            for (int nt = 0; nt < 2; ++nt)
                acc[mt][nt] = MFMA(af[mt], bf[nt], acc[mt][nt]);
        __builtin_amdgcn_s_setprio(0);

        __syncthreads();
    }

#pragma unroll
    for (int mt = 0; mt < 4; ++mt)
#pragma unroll
        for (int nt = 0; nt < 2; ++nt)
#pragma unroll
            for (int r = 0; r < 4; ++r)
                out[(size_t)(m0 + wm * 64 + mt * 16 + quad * 4 + r) * E_ +
                    n0 + wn * 32 + nt * 16 + l16] = acc[mt][nt][r];
#undef OG_STAGE
}

// ---------------------------------------------------------------------------
extern "C" void kernel_launch(void* const* d_in, const int* in_sizes, int n_in,
                              void* d_out, int out_size, void* d_ws, size_t ws_size,
                              hipStream_t stream) {
    const float* q    = (const float*)d_in[0];
    const float* k    = (const float*)d_in[1];
    const float* v    = (const float*)d_in[2];
    const int*   mask = (const int*)d_in[3];
    const float* Wq   = (const float*)d_in[4];
    const float* Wk   = (const float*)d_in[5];
    const float* Wv   = (const float*)d_in[6];
    const float* Wo   = (const float*)d_in[7];
    float* out = (float*)d_out;

    char* ws = (char*)d_ws;
    unsigned short* qh    = (unsigned short*)(ws);
    unsigned short* kh    = (unsigned short*)(ws + (size_t)8 * 1024 * 1024);
    unsigned short* vt    = (unsigned short*)(ws + (size_t)16 * 1024 * 1024);
    unsigned short* attnb = (unsigned short*)(ws + (size_t)24 * 1024 * 1024);

    const bool fused_wo = ws_size >= (size_t)34 * 1024 * 1024;
    unsigned short* wob = fused_wo ? (unsigned short*)(ws + (size_t)32 * 1024 * 1024)
                                   : (unsigned short*)(ws);

    dim3 blk(256);
    proj_kernel<<<dim3(N_ / 64, BH_, fused_wo ? 4 : 3), blk, 0, stream>>>(
        q, k, v, Wq, Wk, Wv, mask, Wo, qh, kh, vt, wob);
    attn_kernel<<<dim3(16, 32), blk, 0, stream>>>(qh, kh, vt, attnb);
    if (!fused_wo)
        cvt_wo_kernel<<<dim3(E_ * E_ / 1024), blk, 0, stream>>>(Wo, wob);
    out_gemm_kernel<<<dim3(256), dim3(512), 0, stream>>>(attnb, wob, out);
}